// Round 3
// baseline (665.223 us; speedup 1.0000x reference)
//
#include <hip/hip_runtime.h>
#include <hip/hip_bf16.h>
#include <math.h>

typedef __attribute__((ext_vector_type(8))) short bf16x8;
typedef __attribute__((ext_vector_type(4))) unsigned short u16x4;
typedef __attribute__((ext_vector_type(4))) float f32x4;

#define MFMA16(a, b, c) __builtin_amdgcn_mfma_f32_16x16x32_bf16(a, b, c, 0, 0, 0)

__device__ inline unsigned short f2bf(float x) {
  union { float f; unsigned u; } v; v.f = x;
  unsigned r = v.u + 0x7FFFu + ((v.u >> 16) & 1u);
  return (unsigned short)(r >> 16);
}

__device__ inline void dma16(const unsigned short* g, unsigned short* l) {
  __builtin_amdgcn_global_load_lds(
      (const __attribute__((address_space(1))) unsigned int*)g,
      (__attribute__((address_space(3))) unsigned int*)l, 16, 0, 0);
}

// All projection weights pre-converted to bf16: [0,16K)=Wq, [16K,48K)=Wkv, [48K,64K)=Wout
__device__ unsigned short g_wbf[65536];

__global__ __launch_bounds__(256) void conv_w(
    const float* __restrict__ Wq, const float* __restrict__ Wkv,
    const float* __restrict__ Wout)
{
  int idx = (blockIdx.x * 256 + threadIdx.x) * 4;   // 64 blocks -> 65536 elems
  const float* src; int off;
  if (idx < 16384)      { src = Wq;   off = idx; }
  else if (idx < 49152) { src = Wkv;  off = idx - 16384; }
  else                  { src = Wout; off = idx - 49152; }
  float4 v = *(const float4*)(src + off);
  u16x4 pk;
  pk.x = f2bf(v.x); pk.y = f2bf(v.y); pk.z = f2bf(v.z); pk.w = f2bf(v.w);
  *(u16x4*)&g_wbf[idx] = pk;
}

// C[m,n] = sum_k A[m,k] * W[n,k]; A fp32 [M,128]; W bf16 from g_wbf at woff(+nt*16384).
// nt==0 -> out0 row-major [M,128] (scaled). nt==1 -> out1 = V^T [bh][128][2048].
__global__ __launch_bounds__(256) void proj_f32(
    const float* __restrict__ A, int woff,
    unsigned short* __restrict__ out0, unsigned short* __restrict__ out1,
    float scale)
{
  const int mbase = blockIdx.x * 64;
  const int nt = blockIdx.y;
  const unsigned short* Wb = g_wbf + woff + nt * 16384;

  __shared__ unsigned short a_s[64 * 136];
  __shared__ unsigned short w_s[128 * 136];

  const int tid = threadIdx.x;
  for (int p = 0; p < 8; ++p) {            // A tile 64x128 fp32 -> bf16
    int r = p * 8 + (tid >> 5);
    int c = tid & 31;
    float4 v = ((const float4*)(A + (size_t)(mbase + r) * 128))[c];
    unsigned short* d = &a_s[r * 136 + c * 4];
    d[0] = f2bf(v.x); d[1] = f2bf(v.y); d[2] = f2bf(v.z); d[3] = f2bf(v.w);
  }
  {
    int r0 = tid >> 4, c = (tid & 15) * 8;
    for (int p = 0; p < 8; ++p) {          // W tile 128x128 bf16
      int r = p * 16 + r0;
      *(bf16x8*)&w_s[r * 136 + c] = *(const bf16x8*)(Wb + (size_t)r * 128 + c);
    }
  }
  __syncthreads();

  const int wave = tid >> 6, lane = tid & 63, quad = lane >> 4, lr = lane & 15;
  f32x4 zero = {0.f, 0.f, 0.f, 0.f};
  f32x4 acc[8];
  for (int nb = 0; nb < 8; ++nb) acc[nb] = zero;

  for (int ks = 0; ks < 4; ++ks) {
    bf16x8 af = *(const bf16x8*)&a_s[(wave * 16 + lr) * 136 + ks * 32 + quad * 8];
    for (int nb = 0; nb < 8; ++nb) {
      bf16x8 bf = *(const bf16x8*)&w_s[(nb * 16 + lr) * 136 + ks * 32 + quad * 8];
      acc[nb] = MFMA16(af, bf, acc[nb]);
    }
  }

  if (nt == 0) {
    for (int nb = 0; nb < 8; ++nb)
      for (int r = 0; r < 4; ++r) {
        int row = mbase + wave * 16 + quad * 4 + r;   // C/D: row = quad*4+reg
        int col = nb * 16 + lr;
        out0[(size_t)row * 128 + col] = f2bf(acc[nb][r] * scale);
      }
  } else {
    int gm = mbase + wave * 16 + quad * 4;            // global row (j-index)
    int bh = gm >> 11;
    int j  = gm & 2047;
    unsigned short* vt = out1 + (size_t)bh * 128 * 2048;
    for (int nb = 0; nb < 8; ++nb) {
      int col = nb * 16 + lr;
      u16x4 pk;
      pk.x = f2bf(acc[nb][0]); pk.y = f2bf(acc[nb][1]);
      pk.z = f2bf(acc[nb][2]); pk.w = f2bf(acc[nb][3]);
      *(u16x4*)&vt[(size_t)col * 2048 + j] = pk;
    }
  }
}

// Flash attention, S^T formulation. Q-tile 256 (wave owns 64 rows = 4 mb),
// J-tile 64. qp pre-scaled by SCALE*log2e, softmax in exp2 domain.
// K/V staged via global_load_lds into XOR-swizzled LDS (no padding allowed by DMA).
// P region is wave-private -> no barrier between P write and PV read. 2 barriers/jt.
__global__ __launch_bounds__(256, 2) void attn_fused(
    const unsigned short* __restrict__ qp,
    const unsigned short* __restrict__ kb,
    const unsigned short* __restrict__ vTb,
    unsigned short* __restrict__ ao)
{
  const int bh = blockIdx.x >> 3;
  const int qt = blockIdx.x & 7;
  const unsigned short* Q  = qp  + (size_t)bh * 2048 * 128 + (size_t)qt * 256 * 128;
  const unsigned short* K  = kb  + (size_t)bh * 2048 * 128;
  const unsigned short* VT = vTb + (size_t)bh * 128 * 2048;
  unsigned short* AO = ao + (size_t)bh * 2048 * 128 + (size_t)qt * 256 * 128;

  __shared__ unsigned short k_s [64 * 128];   // [j][d], 16B chunk c stored at c^(j&15)
  __shared__ unsigned short vT_s[128 * 64];   // [d][j], 16B chunk c stored at c^(d&7)
  __shared__ unsigned short p_s [256 * 64];   // [m][j], 16B chunk c stored at c^(m&7)
  __shared__ float redu_s[4][4][16];          // per-wave alpha / l roundtrip

  const int tid = threadIdx.x;
  const int wave = tid >> 6, lane = tid & 63, quad = lane >> 4, lr = lane & 15;

  bf16x8 qf[4][4];  // Q fragments (B-operand) resident: rows wave*64 + mb*16 + lr
  for (int mb = 0; mb < 4; ++mb)
    for (int ks = 0; ks < 4; ++ks)
      qf[mb][ks] = *(const bf16x8*)(Q + (size_t)(wave * 64 + mb * 16 + lr) * 128 + ks * 32 + quad * 8);

  f32x4 zero = {0.f, 0.f, 0.f, 0.f};
  f32x4 o_acc[4][8];
  float m_i[4], l_i[4];
  for (int mb = 0; mb < 4; ++mb) {
    for (int db = 0; db < 8; ++db) o_acc[mb][db] = zero;
    m_i[mb] = -1e30f; l_i[mb] = 0.f;
  }

  // per-lane DMA source offsets (jt-invariant parts)
  const int kw_i   = wave * 4;                       // first of 4 K-DMA instrs
  const int k_row0 = (lane >> 4);                    // + 4*i
  const int v_row0 = (lane >> 3);                    // + 8*i
  const int v_sc   = ((lane & 7) ^ ((lane >> 3) & 7)) * 8;

  for (int jt = 0; jt < 32; ++jt) {
    __syncthreads();   // all waves done reading k_s/vT_s of previous iter
    for (int p = 0; p < 4; ++p) {
      int i = kw_i + p;
      int rk = 4 * i + k_row0;                       // LDS row 0..63
      int sck = ((lane & 15) ^ (rk & 15)) * 8;
      dma16(K + (size_t)(jt * 64 + rk) * 128 + sck, &k_s[i * 512]);
      int rv = 8 * i + v_row0;                       // LDS row (d) 0..127
      dma16(VT + (size_t)rv * 2048 + jt * 64 + v_sc, &vT_s[i * 512]);
    }
    __syncthreads();   // drains vmcnt -> staging complete

    // ---- S^T = K @ Q^T, softmax, P write (mb in pairs to bound registers) ----
    for (int pr = 0; pr < 2; ++pr) {
      f32x4 sT[2][4];
      for (int mi = 0; mi < 2; ++mi)
        for (int jb = 0; jb < 4; ++jb) sT[mi][jb] = zero;
      for (int ks = 0; ks < 4; ++ks) {
        bf16x8 kf[4];
        for (int jb = 0; jb < 4; ++jb)
          kf[jb] = *(const bf16x8*)&k_s[(jb * 16 + lr) * 128 + (((ks * 4 + quad) ^ lr) << 3)];
        for (int mi = 0; mi < 2; ++mi)
          for (int jb = 0; jb < 4; ++jb)
            sT[mi][jb] = MFMA16(kf[jb], qf[pr * 2 + mi][ks], sT[mi][jb]);
      }
      for (int mi = 0; mi < 2; ++mi) {
        int mb = pr * 2 + mi;
        // per-lane (column m=lr) max over its 16 j's, then combine quads
        float mx = fmaxf(fmaxf(sT[mi][0][0], sT[mi][0][1]), fmaxf(sT[mi][0][2], sT[mi][0][3]));
        for (int jb = 1; jb < 4; ++jb)
          mx = fmaxf(mx, fmaxf(fmaxf(sT[mi][jb][0], sT[mi][jb][1]),
                               fmaxf(sT[mi][jb][2], sT[mi][jb][3])));
        mx = fmaxf(mx, __shfl_xor(mx, 16));
        mx = fmaxf(mx, __shfl_xor(mx, 32));
        float mnew = fmaxf(m_i[mb], mx);
        float alpha = exp2f(m_i[mb] - mnew);
        m_i[mb] = mnew;
        if (lane < 16) redu_s[wave][mb][lane] = alpha;
        float rs = 0.f;
        int prow = wave * 64 + mb * 16 + lr;
        for (int jb = 0; jb < 4; ++jb) {
          float p0 = exp2f(sT[mi][jb][0] - mnew);
          float p1 = exp2f(sT[mi][jb][1] - mnew);
          float p2 = exp2f(sT[mi][jb][2] - mnew);
          float p3 = exp2f(sT[mi][jb][3] - mnew);
          rs += (p0 + p1) + (p2 + p3);
          u16x4 pk;
          pk.x = f2bf(p0); pk.y = f2bf(p1); pk.z = f2bf(p2); pk.w = f2bf(p3);
          int c = jb * 2 + (quad >> 1);
          *(u16x4*)&p_s[prow * 64 + ((c ^ (lr & 7)) << 3) + ((quad & 1) << 2)] = pk;
        }
        rs += __shfl_xor(rs, 16);
        rs += __shfl_xor(rs, 32);
        l_i[mb] = l_i[mb] * alpha + rs;
      }
    }

    // ---- rescale O by alpha (C-layout via wave-local roundtrip), then O += P@V ----
    for (int mb = 0; mb < 4; ++mb) {
      f32x4 av = *(const f32x4*)&redu_s[wave][mb][quad * 4];
      for (int db = 0; db < 8; ++db)
        for (int r = 0; r < 4; ++r) o_acc[mb][db][r] *= av[r];
    }
    for (int ks2 = 0; ks2 < 2; ++ks2) {
      int pc = ((ks2 * 4 + quad) ^ (lr & 7)) << 3;
      bf16x8 pf[4];
      for (int mb = 0; mb < 4; ++mb)
        pf[mb] = *(const bf16x8*)&p_s[(wave * 64 + mb * 16 + lr) * 64 + pc];
      for (int db = 0; db < 8; ++db) {
        bf16x8 vf = *(const bf16x8*)&vT_s[(db * 16 + lr) * 64 + pc];
        for (int mb = 0; mb < 4; ++mb)
          o_acc[mb][db] = MFMA16(pf[mb], vf, o_acc[mb][db]);
      }
    }
  }

  // final: l into C-layout (wave-local roundtrip), normalize, store
  for (int mb = 0; mb < 4; ++mb)
    if (lane < 16) redu_s[wave][mb][lane] = l_i[mb];
  for (int mb = 0; mb < 4; ++mb) {
    f32x4 l4 = *(const f32x4*)&redu_s[wave][mb][quad * 4];
    for (int r = 0; r < 4; ++r) {
      float inv = 1.f / l4[r];
      int row = wave * 64 + mb * 16 + quad * 4 + r;
      for (int db = 0; db < 8; ++db)
        AO[(size_t)row * 128 + db * 16 + lr] = f2bf(o_acc[mb][db][r] * inv);
    }
  }
}

// out[m,e] = sum_d AO[m,d] * Wout[e,d] + bout[e], fp32 output
__global__ __launch_bounds__(256) void proj_out_k(
    const unsigned short* __restrict__ A,
    const float* __restrict__ bias, float* __restrict__ out)
{
  const int mbase = blockIdx.x * 64;
  const unsigned short* Wb = g_wbf + 49152;
  __shared__ unsigned short a_s[64 * 136];
  __shared__ unsigned short w_s[128 * 136];
  const int tid = threadIdx.x;
  {
    int r0 = tid >> 4, c = (tid & 15) * 8;
    for (int p = 0; p < 4; ++p)
      *(bf16x8*)&a_s[(p * 16 + r0) * 136 + c] =
          *(const bf16x8*)(A + (size_t)(mbase + p * 16 + r0) * 128 + c);
    for (int p = 0; p < 8; ++p)
      *(bf16x8*)&w_s[(p * 16 + r0) * 136 + c] =
          *(const bf16x8*)(Wb + (size_t)(p * 16 + r0) * 128 + c);
  }
  __syncthreads();
  const int wave = tid >> 6, lane = tid & 63, quad = lane >> 4, lr = lane & 15;
  f32x4 zero = {0.f, 0.f, 0.f, 0.f};
  f32x4 acc[8];
  for (int nb = 0; nb < 8; ++nb) acc[nb] = zero;
  for (int ks = 0; ks < 4; ++ks) {
    bf16x8 af = *(const bf16x8*)&a_s[(wave * 16 + lr) * 136 + ks * 32 + quad * 8];
    for (int nb = 0; nb < 8; ++nb) {
      bf16x8 bf = *(const bf16x8*)&w_s[(nb * 16 + lr) * 136 + ks * 32 + quad * 8];
      acc[nb] = MFMA16(af, bf, acc[nb]);
    }
  }
  for (int nb = 0; nb < 8; ++nb)
    for (int r = 0; r < 4; ++r) {
      int row = mbase + wave * 16 + quad * 4 + r;
      int col = nb * 16 + lr;
      out[(size_t)row * 128 + col] = acc[nb][r] + bias[col];
    }
}

extern "C" void kernel_launch(void* const* d_in, const int* in_sizes, int n_in,
                              void* d_out, int out_size, void* d_ws, size_t ws_size,
                              hipStream_t stream) {
  const float* q    = (const float*)d_in[0];
  const float* kv   = (const float*)d_in[1];
  const float* Wq   = (const float*)d_in[2];
  const float* Wkv  = (const float*)d_in[3];
  const float* Wout = (const float*)d_in[4];
  const float* bout = (const float*)d_in[5];
  float* out = (float*)d_out;

  const size_t NELEM = (size_t)131072 * 128;
  unsigned short* qp_b = (unsigned short*)d_ws;
  unsigned short* k_b  = qp_b + NELEM;
  unsigned short* vT_b = k_b + NELEM;   // [bh][128][2048]
  unsigned short* ao_b = vT_b + NELEM;

  // 128^-0.5 * log2(e): softmax computed in exp2 domain
  const float SCALE2 = 0.08838834764831845f * 1.4426950408889634f;

  conv_w<<<dim3(64), 256, 0, stream>>>(Wq, Wkv, Wout);
  proj_f32<<<dim3(2048, 1), 256, 0, stream>>>(q, 0, qp_b, qp_b, SCALE2);
  proj_f32<<<dim3(2048, 2), 256, 0, stream>>>(kv, 16384, k_b, vT_b, 1.0f);
  attn_fused<<<dim3(512), 256, 0, stream>>>(qp_b, k_b, vT_b, ao_b);
  proj_out_k<<<dim3(2048), 256, 0, stream>>>(ao_b, bout, out);
}

// Round 4
// 621.565 us; speedup vs baseline: 1.0702x; 1.0702x over previous
//
#include <hip/hip_runtime.h>
#include <hip/hip_bf16.h>
#include <math.h>

typedef __attribute__((ext_vector_type(8))) short bf16x8;
typedef __attribute__((ext_vector_type(4))) unsigned short u16x4;
typedef __attribute__((ext_vector_type(4))) float f32x4;

#define MFMA16(a, b, c) __builtin_amdgcn_mfma_f32_16x16x32_bf16(a, b, c, 0, 0, 0)

__device__ inline unsigned short f2bf(float x) {
  union { float f; unsigned u; } v; v.f = x;
  unsigned r = v.u + 0x7FFFu + ((v.u >> 16) & 1u);
  return (unsigned short)(r >> 16);
}

__device__ inline void dma16(const unsigned short* g, unsigned short* l) {
  __builtin_amdgcn_global_load_lds(
      (const __attribute__((address_space(1))) unsigned int*)g,
      (__attribute__((address_space(3))) unsigned int*)l, 16, 0, 0);
}

// All projection weights pre-converted to bf16: [0,16K)=Wq, [16K,48K)=Wkv, [48K,64K)=Wout
__device__ unsigned short g_wbf[65536];

__global__ __launch_bounds__(256) void conv_w(
    const float* __restrict__ Wq, const float* __restrict__ Wkv,
    const float* __restrict__ Wout)
{
  int idx = (blockIdx.x * 256 + threadIdx.x) * 4;   // 64 blocks -> 65536 elems
  const float* src; int off;
  if (idx < 16384)      { src = Wq;   off = idx; }
  else if (idx < 49152) { src = Wkv;  off = idx - 16384; }
  else                  { src = Wout; off = idx - 49152; }
  float4 v = *(const float4*)(src + off);
  u16x4 pk;
  pk.x = f2bf(v.x); pk.y = f2bf(v.y); pk.z = f2bf(v.z); pk.w = f2bf(v.w);
  *(u16x4*)&g_wbf[idx] = pk;
}

// C[m,n] = sum_k A[m,k] * W[n,k]; A fp32 [M,128]; W bf16 from g_wbf at woff(+nt*16384).
// nt==0 -> out0 row-major [M,128] (scaled). nt==1 -> out1 = V^T [bh][128][2048].
__global__ __launch_bounds__(256) void proj_f32(
    const float* __restrict__ A, int woff,
    unsigned short* __restrict__ out0, unsigned short* __restrict__ out1,
    float scale)
{
  const int mbase = blockIdx.x * 64;
  const int nt = blockIdx.y;
  const unsigned short* Wb = g_wbf + woff + nt * 16384;

  __shared__ unsigned short a_s[64 * 136];
  __shared__ unsigned short w_s[128 * 136];

  const int tid = threadIdx.x;
  for (int p = 0; p < 8; ++p) {            // A tile 64x128 fp32 -> bf16, 8B stores
    int r = p * 8 + (tid >> 5);
    int c = tid & 31;
    float4 v = ((const float4*)(A + (size_t)(mbase + r) * 128))[c];
    u16x4 pk;
    pk.x = f2bf(v.x); pk.y = f2bf(v.y); pk.z = f2bf(v.z); pk.w = f2bf(v.w);
    *(u16x4*)&a_s[r * 136 + c * 4] = pk;
  }
  {
    int r0 = tid >> 4, c = (tid & 15) * 8;
    for (int p = 0; p < 8; ++p) {          // W tile 128x128 bf16
      int r = p * 16 + r0;
      *(bf16x8*)&w_s[r * 136 + c] = *(const bf16x8*)(Wb + (size_t)r * 128 + c);
    }
  }
  __syncthreads();

  const int wave = tid >> 6, lane = tid & 63, quad = lane >> 4, lr = lane & 15;
  f32x4 zero = {0.f, 0.f, 0.f, 0.f};
  f32x4 acc[8];
  for (int nb = 0; nb < 8; ++nb) acc[nb] = zero;

  for (int ks = 0; ks < 4; ++ks) {
    bf16x8 af = *(const bf16x8*)&a_s[(wave * 16 + lr) * 136 + ks * 32 + quad * 8];
    for (int nb = 0; nb < 8; ++nb) {
      bf16x8 bf = *(const bf16x8*)&w_s[(nb * 16 + lr) * 136 + ks * 32 + quad * 8];
      acc[nb] = MFMA16(af, bf, acc[nb]);
    }
  }

  if (nt == 0) {
    for (int nb = 0; nb < 8; ++nb)
      for (int r = 0; r < 4; ++r) {
        int row = mbase + wave * 16 + quad * 4 + r;   // C/D: row = quad*4+reg
        int col = nb * 16 + lr;
        out0[(size_t)row * 128 + col] = f2bf(acc[nb][r] * scale);
      }
  } else {
    int gm = mbase + wave * 16 + quad * 4;            // global row (j-index)
    int bh = gm >> 11;
    int j  = gm & 2047;
    unsigned short* vt = out1 + (size_t)bh * 128 * 2048;
    for (int nb = 0; nb < 8; ++nb) {
      int col = nb * 16 + lr;
      u16x4 pk;
      pk.x = f2bf(acc[nb][0]); pk.y = f2bf(acc[nb][1]);
      pk.z = f2bf(acc[nb][2]); pk.w = f2bf(acc[nb][3]);
      *(u16x4*)&vt[(size_t)col * 2048 + j] = pk;
    }
  }
}

// Flash attention, S^T formulation, software-pipelined DMA:
//   per jt: issue V(jt) -> S^T (k_s) -> barrier(drain V) -> issue K(jt+1)
//           -> rescale + PV (vT_s, p_s) -> barrier(drain K).
// Each DMA has a full compute phase in flight before its vmcnt(0) drain.
// Block swizzle pins all 8 qt-tiles of one bh to one XCD (L2 stream sharing).
__global__ __launch_bounds__(256, 2) void attn_fused(
    const unsigned short* __restrict__ qp,
    const unsigned short* __restrict__ kb,
    const unsigned short* __restrict__ vTb,
    unsigned short* __restrict__ ao)
{
  const int xcd = blockIdx.x & 7;
  const int loc = blockIdx.x >> 3;
  const int qt  = loc & 7;
  const int bh  = (loc >> 3) * 8 + xcd;   // all qt of a bh share an XCD
  const unsigned short* Q  = qp  + (size_t)bh * 2048 * 128 + (size_t)qt * 256 * 128;
  const unsigned short* K  = kb  + (size_t)bh * 2048 * 128;
  const unsigned short* VT = vTb + (size_t)bh * 128 * 2048;
  unsigned short* AO = ao + (size_t)bh * 2048 * 128 + (size_t)qt * 256 * 128;

  __shared__ unsigned short k_s [64 * 128];   // [j][d], 16B chunk c at c^(j&15)
  __shared__ unsigned short vT_s[128 * 64];   // [d][j], 16B chunk c at c^(d&7)
  __shared__ unsigned short p_s [256 * 64];   // [m][j], 16B chunk c at c^(m&7)
  __shared__ float redu_s[4][4][16];          // per-wave alpha / l roundtrip

  const int tid = threadIdx.x;
  const int wave = tid >> 6, lane = tid & 63, quad = lane >> 4, lr = lane & 15;

  // per-lane DMA offsets (jt-invariant parts)
  const int kw_i   = wave * 4;
  const int k_row0 = (lane >> 4);
  const int v_row0 = (lane >> 3);
  const int v_sc   = ((lane & 7) ^ ((lane >> 3) & 7)) * 8;

  // prologue: K(0) in flight while Q fragments load
  for (int p = 0; p < 4; ++p) {
    int i = kw_i + p;
    int rk = 4 * i + k_row0;
    int sck = ((lane & 15) ^ (rk & 15)) * 8;
    dma16(K + (size_t)rk * 128 + sck, &k_s[i * 512]);
  }

  bf16x8 qf[4][4];  // Q fragments (B-operand) resident: rows wave*64 + mb*16 + lr
  for (int mb = 0; mb < 4; ++mb)
    for (int ks = 0; ks < 4; ++ks)
      qf[mb][ks] = *(const bf16x8*)(Q + (size_t)(wave * 64 + mb * 16 + lr) * 128 + ks * 32 + quad * 8);

  f32x4 zero = {0.f, 0.f, 0.f, 0.f};
  f32x4 o_acc[4][8];
  float m_i[4], l_i[4];
  for (int mb = 0; mb < 4; ++mb) {
    for (int db = 0; db < 8; ++db) o_acc[mb][db] = zero;
    m_i[mb] = -1e30f; l_i[mb] = 0.f;
  }

  __syncthreads();   // drains K(0)

  for (int jt = 0; jt < 32; ++jt) {
    // issue V(jt); its drain is the barrier AFTER S^T
    for (int p = 0; p < 4; ++p) {
      int i = kw_i + p;
      int rv = 8 * i + v_row0;
      dma16(VT + (size_t)rv * 2048 + jt * 64 + v_sc, &vT_s[i * 512]);
    }

    // ---- S^T = K @ Q^T, softmax, P write (k_s only) ----
    for (int pr = 0; pr < 2; ++pr) {
      f32x4 sT[2][4];
      for (int mi = 0; mi < 2; ++mi)
        for (int jb = 0; jb < 4; ++jb) sT[mi][jb] = zero;
      for (int ks = 0; ks < 4; ++ks) {
        bf16x8 kf[4];
        for (int jb = 0; jb < 4; ++jb)
          kf[jb] = *(const bf16x8*)&k_s[(jb * 16 + lr) * 128 + (((ks * 4 + quad) ^ lr) << 3)];
        for (int mi = 0; mi < 2; ++mi)
          for (int jb = 0; jb < 4; ++jb)
            sT[mi][jb] = MFMA16(kf[jb], qf[pr * 2 + mi][ks], sT[mi][jb]);
      }
      for (int mi = 0; mi < 2; ++mi) {
        int mb = pr * 2 + mi;
        float mx = fmaxf(fmaxf(sT[mi][0][0], sT[mi][0][1]), fmaxf(sT[mi][0][2], sT[mi][0][3]));
        for (int jb = 1; jb < 4; ++jb)
          mx = fmaxf(mx, fmaxf(fmaxf(sT[mi][jb][0], sT[mi][jb][1]),
                               fmaxf(sT[mi][jb][2], sT[mi][jb][3])));
        mx = fmaxf(mx, __shfl_xor(mx, 16));
        mx = fmaxf(mx, __shfl_xor(mx, 32));
        float mnew = fmaxf(m_i[mb], mx);
        float alpha = exp2f(m_i[mb] - mnew);
        m_i[mb] = mnew;
        if (lane < 16) redu_s[wave][mb][lane] = alpha;
        float rs = 0.f;
        int prow = wave * 64 + mb * 16 + lr;
        for (int jb = 0; jb < 4; ++jb) {
          float p0 = exp2f(sT[mi][jb][0] - mnew);
          float p1 = exp2f(sT[mi][jb][1] - mnew);
          float p2 = exp2f(sT[mi][jb][2] - mnew);
          float p3 = exp2f(sT[mi][jb][3] - mnew);
          rs += (p0 + p1) + (p2 + p3);
          u16x4 pk;
          pk.x = f2bf(p0); pk.y = f2bf(p1); pk.z = f2bf(p2); pk.w = f2bf(p3);
          int c = jb * 2 + (quad >> 1);
          *(u16x4*)&p_s[prow * 64 + ((c ^ (lr & 7)) << 3) + ((quad & 1) << 2)] = pk;
        }
        rs += __shfl_xor(rs, 16);
        rs += __shfl_xor(rs, 32);
        l_i[mb] = l_i[mb] * alpha + rs;
      }
    }

    __syncthreads();   // drains V(jt); all waves done with k_s

    // issue K(jt+1); its drain is the barrier AFTER PV
    if (jt < 31) {
      const unsigned short* Kn = K + (size_t)(jt + 1) * 64 * 128;
      for (int p = 0; p < 4; ++p) {
        int i = kw_i + p;
        int rk = 4 * i + k_row0;
        int sck = ((lane & 15) ^ (rk & 15)) * 8;
        dma16(Kn + (size_t)rk * 128 + sck, &k_s[i * 512]);
      }
    }

    // ---- rescale O by alpha, then O += P@V (vT_s, p_s only) ----
    for (int mb = 0; mb < 4; ++mb) {
      f32x4 av = *(const f32x4*)&redu_s[wave][mb][quad * 4];
      for (int db = 0; db < 8; ++db)
        for (int r = 0; r < 4; ++r) o_acc[mb][db][r] *= av[r];
    }
    for (int ks2 = 0; ks2 < 2; ++ks2) {
      int pc = ((ks2 * 4 + quad) ^ (lr & 7)) << 3;
      bf16x8 pf[4];
      for (int mb = 0; mb < 4; ++mb)
        pf[mb] = *(const bf16x8*)&p_s[(wave * 64 + mb * 16 + lr) * 64 + pc];
      for (int db = 0; db < 8; ++db) {
        bf16x8 vf = *(const bf16x8*)&vT_s[(db * 16 + lr) * 64 + pc];
        for (int mb = 0; mb < 4; ++mb)
          o_acc[mb][db] = MFMA16(pf[mb], vf, o_acc[mb][db]);
      }
    }

    __syncthreads();   // drains K(jt+1); all waves done with vT_s
  }

  // final: l into C-layout (wave-local roundtrip), normalize, store
  for (int mb = 0; mb < 4; ++mb)
    if (lane < 16) redu_s[wave][mb][lane] = l_i[mb];
  for (int mb = 0; mb < 4; ++mb) {
    f32x4 l4 = *(const f32x4*)&redu_s[wave][mb][quad * 4];
    for (int r = 0; r < 4; ++r) {
      float inv = 1.f / l4[r];
      int row = wave * 64 + mb * 16 + quad * 4 + r;
      for (int db = 0; db < 8; ++db)
        AO[(size_t)row * 128 + db * 16 + lr] = f2bf(o_acc[mb][db][r] * inv);
    }
  }
}

// out[m,e] = sum_d AO[m,d] * Wout[e,d] + bout[e], fp32 output
__global__ __launch_bounds__(256) void proj_out_k(
    const unsigned short* __restrict__ A,
    const float* __restrict__ bias, float* __restrict__ out)
{
  const int mbase = blockIdx.x * 64;
  const unsigned short* Wb = g_wbf + 49152;
  __shared__ unsigned short a_s[64 * 136];
  __shared__ unsigned short w_s[128 * 136];
  const int tid = threadIdx.x;
  {
    int r0 = tid >> 4, c = (tid & 15) * 8;
    for (int p = 0; p < 4; ++p)
      *(bf16x8*)&a_s[(p * 16 + r0) * 136 + c] =
          *(const bf16x8*)(A + (size_t)(mbase + p * 16 + r0) * 128 + c);
    for (int p = 0; p < 8; ++p)
      *(bf16x8*)&w_s[(p * 16 + r0) * 136 + c] =
          *(const bf16x8*)(Wb + (size_t)(p * 16 + r0) * 128 + c);
  }
  __syncthreads();
  const int wave = tid >> 6, lane = tid & 63, quad = lane >> 4, lr = lane & 15;
  f32x4 zero = {0.f, 0.f, 0.f, 0.f};
  f32x4 acc[8];
  for (int nb = 0; nb < 8; ++nb) acc[nb] = zero;
  for (int ks = 0; ks < 4; ++ks) {
    bf16x8 af = *(const bf16x8*)&a_s[(wave * 16 + lr) * 136 + ks * 32 + quad * 8];
    for (int nb = 0; nb < 8; ++nb) {
      bf16x8 bf = *(const bf16x8*)&w_s[(nb * 16 + lr) * 136 + ks * 32 + quad * 8];
      acc[nb] = MFMA16(af, bf, acc[nb]);
    }
  }
  for (int nb = 0; nb < 8; ++nb)
    for (int r = 0; r < 4; ++r) {
      int row = mbase + wave * 16 + quad * 4 + r;
      int col = nb * 16 + lr;
      out[(size_t)row * 128 + col] = acc[nb][r] + bias[col];
    }
}

extern "C" void kernel_launch(void* const* d_in, const int* in_sizes, int n_in,
                              void* d_out, int out_size, void* d_ws, size_t ws_size,
                              hipStream_t stream) {
  const float* q    = (const float*)d_in[0];
  const float* kv   = (const float*)d_in[1];
  const float* Wq   = (const float*)d_in[2];
  const float* Wkv  = (const float*)d_in[3];
  const float* Wout = (const float*)d_in[4];
  const float* bout = (const float*)d_in[5];
  float* out = (float*)d_out;

  const size_t NELEM = (size_t)131072 * 128;
  unsigned short* qp_b = (unsigned short*)d_ws;
  unsigned short* k_b  = qp_b + NELEM;
  unsigned short* vT_b = k_b + NELEM;   // [bh][128][2048]
  unsigned short* ao_b = vT_b + NELEM;

  // 128^-0.5 * log2(e): softmax computed in exp2 domain
  const float SCALE2 = 0.08838834764831845f * 1.4426950408889634f;

  conv_w<<<dim3(64), 256, 0, stream>>>(Wq, Wkv, Wout);
  proj_f32<<<dim3(2048, 1), 256, 0, stream>>>(q, 0, qp_b, qp_b, SCALE2);
  proj_f32<<<dim3(2048, 2), 256, 0, stream>>>(kv, 16384, k_b, vT_b, 1.0f);
  attn_fused<<<dim3(512), 256, 0, stream>>>(qp_b, k_b, vT_b, ao_b);
  proj_out_k<<<dim3(2048), 256, 0, stream>>>(ao_b, bout, out);
}

// Round 5
// 601.288 us; speedup vs baseline: 1.1063x; 1.0337x over previous
//
#include <hip/hip_runtime.h>
#include <hip/hip_bf16.h>
#include <math.h>

typedef __attribute__((ext_vector_type(8))) short bf16x8;
typedef __attribute__((ext_vector_type(4))) unsigned short u16x4;
typedef __attribute__((ext_vector_type(4))) float f32x4;

#define MFMA16(a, b, c) __builtin_amdgcn_mfma_f32_16x16x32_bf16(a, b, c, 0, 0, 0)

__device__ inline unsigned short f2bf(float x) {
  union { float f; unsigned u; } v; v.f = x;
  unsigned r = v.u + 0x7FFFu + ((v.u >> 16) & 1u);
  return (unsigned short)(r >> 16);
}

__device__ inline void dma16(const unsigned short* g, unsigned short* l) {
  __builtin_amdgcn_global_load_lds(
      (const __attribute__((address_space(1))) unsigned int*)g,
      (__attribute__((address_space(3))) unsigned int*)l, 16, 0, 0);
}

// All projection weights pre-converted to bf16: [0,16K)=Wq, [16K,48K)=Wkv, [48K,64K)=Wout
__device__ unsigned short g_wbf[65536];

__global__ __launch_bounds__(256) void conv_w(
    const float* __restrict__ Wq, const float* __restrict__ Wkv,
    const float* __restrict__ Wout)
{
  int idx = (blockIdx.x * 256 + threadIdx.x) * 4;   // 64 blocks -> 65536 elems
  const float* src; int off;
  if (idx < 16384)      { src = Wq;   off = idx; }
  else if (idx < 49152) { src = Wkv;  off = idx - 16384; }
  else                  { src = Wout; off = idx - 49152; }
  float4 v = *(const float4*)(src + off);
  u16x4 pk;
  pk.x = f2bf(v.x); pk.y = f2bf(v.y); pk.z = f2bf(v.z); pk.w = f2bf(v.w);
  *(u16x4*)&g_wbf[idx] = pk;
}

// q projection: C[m,n] = sum_k A[m,k]*Wq[n,k], scaled, row-major bf16 out.
__global__ __launch_bounds__(256) void proj_q(
    const float* __restrict__ A, unsigned short* __restrict__ out0, float scale)
{
  const int mbase = blockIdx.x * 64;
  const unsigned short* Wb = g_wbf;

  __shared__ unsigned short a_s[64 * 136];
  __shared__ unsigned short w_s[128 * 136];

  const int tid = threadIdx.x;
  for (int p = 0; p < 8; ++p) {
    int r = p * 8 + (tid >> 5);
    int c = tid & 31;
    float4 v = ((const float4*)(A + (size_t)(mbase + r) * 128))[c];
    u16x4 pk;
    pk.x = f2bf(v.x); pk.y = f2bf(v.y); pk.z = f2bf(v.z); pk.w = f2bf(v.w);
    *(u16x4*)&a_s[r * 136 + c * 4] = pk;
  }
  {
    int r0 = tid >> 4, c = (tid & 15) * 8;
    for (int p = 0; p < 8; ++p) {
      int r = p * 16 + r0;
      *(bf16x8*)&w_s[r * 136 + c] = *(const bf16x8*)(Wb + (size_t)r * 128 + c);
    }
  }
  __syncthreads();

  const int wave = tid >> 6, lane = tid & 63, quad = lane >> 4, lr = lane & 15;
  f32x4 zero = {0.f, 0.f, 0.f, 0.f};
  f32x4 acc[8];
  for (int nb = 0; nb < 8; ++nb) acc[nb] = zero;
  for (int ks = 0; ks < 4; ++ks) {
    bf16x8 af = *(const bf16x8*)&a_s[(wave * 16 + lr) * 136 + ks * 32 + quad * 8];
    for (int nb = 0; nb < 8; ++nb) {
      bf16x8 bf = *(const bf16x8*)&w_s[(nb * 16 + lr) * 136 + ks * 32 + quad * 8];
      acc[nb] = MFMA16(af, bf, acc[nb]);
    }
  }
  for (int nb = 0; nb < 8; ++nb)
    for (int r = 0; r < 4; ++r) {
      int row = mbase + wave * 16 + quad * 4 + r;
      int col = nb * 16 + lr;
      out0[(size_t)row * 128 + col] = f2bf(acc[nb][r] * scale);
    }
}

// kv projection, both halves from ONE A staging: nt=0 -> K row-major,
// nt=1 -> V^T [bh][128][2048].
__global__ __launch_bounds__(256) void proj_kv(
    const float* __restrict__ A,
    unsigned short* __restrict__ outK, unsigned short* __restrict__ outVT)
{
  const int mbase = blockIdx.x * 64;
  __shared__ unsigned short a_s[64 * 136];
  __shared__ unsigned short w_s[128 * 136];
  const int tid = threadIdx.x;

  for (int p = 0; p < 8; ++p) {
    int r = p * 8 + (tid >> 5);
    int c = tid & 31;
    float4 v = ((const float4*)(A + (size_t)(mbase + r) * 128))[c];
    u16x4 pk;
    pk.x = f2bf(v.x); pk.y = f2bf(v.y); pk.z = f2bf(v.z); pk.w = f2bf(v.w);
    *(u16x4*)&a_s[r * 136 + c * 4] = pk;
  }

  const int wave = tid >> 6, lane = tid & 63, quad = lane >> 4, lr = lane & 15;
  f32x4 zero = {0.f, 0.f, 0.f, 0.f};

  for (int nt = 0; nt < 2; ++nt) {
    __syncthreads();   // nt=0: A staged; nt=1: all w_s reads done
    {
      const unsigned short* Wb = g_wbf + 16384 + nt * 16384;
      int r0 = tid >> 4, c = (tid & 15) * 8;
      for (int p = 0; p < 8; ++p) {
        int r = p * 16 + r0;
        *(bf16x8*)&w_s[r * 136 + c] = *(const bf16x8*)(Wb + (size_t)r * 128 + c);
      }
    }
    __syncthreads();

    f32x4 acc[8];
    for (int nb = 0; nb < 8; ++nb) acc[nb] = zero;
    for (int ks = 0; ks < 4; ++ks) {
      bf16x8 af = *(const bf16x8*)&a_s[(wave * 16 + lr) * 136 + ks * 32 + quad * 8];
      for (int nb = 0; nb < 8; ++nb) {
        bf16x8 bf = *(const bf16x8*)&w_s[(nb * 16 + lr) * 136 + ks * 32 + quad * 8];
        acc[nb] = MFMA16(af, bf, acc[nb]);
      }
    }

    if (nt == 0) {
      for (int nb = 0; nb < 8; ++nb)
        for (int r = 0; r < 4; ++r) {
          int row = mbase + wave * 16 + quad * 4 + r;
          int col = nb * 16 + lr;
          outK[(size_t)row * 128 + col] = f2bf(acc[nb][r]);
        }
    } else {
      int gm = mbase + wave * 16 + quad * 4;
      int bh = gm >> 11;
      int j  = gm & 2047;
      unsigned short* vt = outVT + (size_t)bh * 128 * 2048;
      for (int nb = 0; nb < 8; ++nb) {
        int col = nb * 16 + lr;
        u16x4 pk;
        pk.x = f2bf(acc[nb][0]); pk.y = f2bf(acc[nb][1]);
        pk.z = f2bf(acc[nb][2]); pk.w = f2bf(acc[nb][3]);
        *(u16x4*)&vt[(size_t)col * 2048 + j] = pk;
      }
    }
  }
}

// Flash attention, S^T formulation, Q-tile 512 (512 threads, 8 waves x 64 rows),
// J-tile 64, pipelined DMA (2 barriers/jt), XOR-swizzled LDS.
// K/V passes per bh: 4 (was 8) -> K/V HBM traffic halved.
__global__ __launch_bounds__(512, 2) void attn_fused(
    const unsigned short* __restrict__ qp,
    const unsigned short* __restrict__ kb,
    const unsigned short* __restrict__ vTb,
    unsigned short* __restrict__ ao)
{
  const int xcd = blockIdx.x & 7;
  const int loc = blockIdx.x >> 3;
  const int qt  = loc & 3;
  const int bh  = (loc >> 2) * 8 + xcd;   // 4 qt-blocks of a bh share an XCD
  const unsigned short* Q  = qp  + (size_t)bh * 2048 * 128 + (size_t)qt * 512 * 128;
  const unsigned short* K  = kb  + (size_t)bh * 2048 * 128;
  const unsigned short* VT = vTb + (size_t)bh * 128 * 2048;
  unsigned short* AO = ao + (size_t)bh * 2048 * 128 + (size_t)qt * 512 * 128;

  __shared__ unsigned short k_s [64 * 128];   // [j][d], 16B chunk c at c^(j&15)
  __shared__ unsigned short vT_s[128 * 64];   // [d][j], 16B chunk c at c^(d&7)
  __shared__ unsigned short p_s [512 * 64];   // [m][j], 16B chunk c at c^(m&7)
  __shared__ float redu_s[8][4][16];          // per-wave alpha / l roundtrip

  const int tid = threadIdx.x;
  const int wave = tid >> 6, lane = tid & 63, quad = lane >> 4, lr = lane & 15;

  // per-lane DMA offsets: 16 dma16 instrs cover each 16KB tile; 2 per wave
  const int kw_i   = wave * 2;
  const int k_row0 = (lane >> 4);
  const int v_row0 = (lane >> 3);
  const int v_sc   = ((lane & 7) ^ ((lane >> 3) & 7)) * 8;

  // prologue: K(0) in flight while Q fragments load
  for (int p = 0; p < 2; ++p) {
    int i = kw_i + p;
    int rk = 4 * i + k_row0;
    int sck = ((lane & 15) ^ (rk & 15)) * 8;
    dma16(K + (size_t)rk * 128 + sck, &k_s[i * 512]);
  }

  bf16x8 qf[4][4];  // Q fragments (B-operand): rows wave*64 + mb*16 + lr
  for (int mb = 0; mb < 4; ++mb)
    for (int ks = 0; ks < 4; ++ks)
      qf[mb][ks] = *(const bf16x8*)(Q + (size_t)(wave * 64 + mb * 16 + lr) * 128 + ks * 32 + quad * 8);

  f32x4 zero = {0.f, 0.f, 0.f, 0.f};
  f32x4 o_acc[4][8];
  float m_i[4], l_i[4];
  for (int mb = 0; mb < 4; ++mb) {
    for (int db = 0; db < 8; ++db) o_acc[mb][db] = zero;
    m_i[mb] = -1e30f; l_i[mb] = 0.f;
  }

  __syncthreads();   // drains K(0)

  for (int jt = 0; jt < 32; ++jt) {
    // issue V(jt); its drain is the barrier AFTER S^T
    for (int p = 0; p < 2; ++p) {
      int i = kw_i + p;
      int rv = 8 * i + v_row0;
      dma16(VT + (size_t)rv * 2048 + jt * 64 + v_sc, &vT_s[i * 512]);
    }

    // ---- S^T = K @ Q^T, softmax, P write (k_s only) ----
    for (int pr = 0; pr < 2; ++pr) {
      f32x4 sT[2][4];
      for (int mi = 0; mi < 2; ++mi)
        for (int jb = 0; jb < 4; ++jb) sT[mi][jb] = zero;
      for (int ks = 0; ks < 4; ++ks) {
        bf16x8 kf[4];
        for (int jb = 0; jb < 4; ++jb)
          kf[jb] = *(const bf16x8*)&k_s[(jb * 16 + lr) * 128 + (((ks * 4 + quad) ^ lr) << 3)];
        for (int mi = 0; mi < 2; ++mi)
          for (int jb = 0; jb < 4; ++jb)
            sT[mi][jb] = MFMA16(kf[jb], qf[pr * 2 + mi][ks], sT[mi][jb]);
      }
      for (int mi = 0; mi < 2; ++mi) {
        int mb = pr * 2 + mi;
        float mx = fmaxf(fmaxf(sT[mi][0][0], sT[mi][0][1]), fmaxf(sT[mi][0][2], sT[mi][0][3]));
        for (int jb = 1; jb < 4; ++jb)
          mx = fmaxf(mx, fmaxf(fmaxf(sT[mi][jb][0], sT[mi][jb][1]),
                               fmaxf(sT[mi][jb][2], sT[mi][jb][3])));
        mx = fmaxf(mx, __shfl_xor(mx, 16));
        mx = fmaxf(mx, __shfl_xor(mx, 32));
        float mnew = fmaxf(m_i[mb], mx);
        float alpha = exp2f(m_i[mb] - mnew);
        m_i[mb] = mnew;
        if (lane < 16) redu_s[wave][mb][lane] = alpha;
        float rs = 0.f;
        int prow = wave * 64 + mb * 16 + lr;
        for (int jb = 0; jb < 4; ++jb) {
          float p0 = exp2f(sT[mi][jb][0] - mnew);
          float p1 = exp2f(sT[mi][jb][1] - mnew);
          float p2 = exp2f(sT[mi][jb][2] - mnew);
          float p3 = exp2f(sT[mi][jb][3] - mnew);
          rs += (p0 + p1) + (p2 + p3);
          u16x4 pk;
          pk.x = f2bf(p0); pk.y = f2bf(p1); pk.z = f2bf(p2); pk.w = f2bf(p3);
          int c = jb * 2 + (quad >> 1);
          *(u16x4*)&p_s[prow * 64 + ((c ^ (lr & 7)) << 3) + ((quad & 1) << 2)] = pk;
        }
        rs += __shfl_xor(rs, 16);
        rs += __shfl_xor(rs, 32);
        l_i[mb] = l_i[mb] * alpha + rs;
      }
    }

    __syncthreads();   // drains V(jt); all waves done with k_s

    // issue K(jt+1); its drain is the barrier AFTER PV
    if (jt < 31) {
      const unsigned short* Kn = K + (size_t)(jt + 1) * 64 * 128;
      for (int p = 0; p < 2; ++p) {
        int i = kw_i + p;
        int rk = 4 * i + k_row0;
        int sck = ((lane & 15) ^ (rk & 15)) * 8;
        dma16(Kn + (size_t)rk * 128 + sck, &k_s[i * 512]);
      }
    }

    // ---- rescale O by alpha, then O += P@V (vT_s, p_s only) ----
    for (int mb = 0; mb < 4; ++mb) {
      f32x4 av = *(const f32x4*)&redu_s[wave][mb][quad * 4];
      for (int db = 0; db < 8; ++db)
        for (int r = 0; r < 4; ++r) o_acc[mb][db][r] *= av[r];
    }
    for (int ks2 = 0; ks2 < 2; ++ks2) {
      int pc = ((ks2 * 4 + quad) ^ (lr & 7)) << 3;
      bf16x8 pf[4];
      for (int mb = 0; mb < 4; ++mb)
        pf[mb] = *(const bf16x8*)&p_s[(wave * 64 + mb * 16 + lr) * 64 + pc];
      for (int db = 0; db < 8; ++db) {
        bf16x8 vf = *(const bf16x8*)&vT_s[(db * 16 + lr) * 64 + pc];
        for (int mb = 0; mb < 4; ++mb)
          o_acc[mb][db] = MFMA16(pf[mb], vf, o_acc[mb][db]);
      }
    }

    __syncthreads();   // drains K(jt+1); all waves done with vT_s
  }

  // final: l into C-layout (wave-local roundtrip), normalize, store
  for (int mb = 0; mb < 4; ++mb)
    if (lane < 16) redu_s[wave][mb][lane] = l_i[mb];
  for (int mb = 0; mb < 4; ++mb) {
    f32x4 l4 = *(const f32x4*)&redu_s[wave][mb][quad * 4];
    for (int r = 0; r < 4; ++r) {
      float inv = 1.f / l4[r];
      int row = wave * 64 + mb * 16 + quad * 4 + r;
      for (int db = 0; db < 8; ++db)
        AO[(size_t)row * 128 + db * 16 + lr] = f2bf(o_acc[mb][db][r] * inv);
    }
  }
}

// out[m,e] = sum_d AO[m,d] * Wout[e,d] + bout[e], fp32 output
__global__ __launch_bounds__(256) void proj_out_k(
    const unsigned short* __restrict__ A,
    const float* __restrict__ bias, float* __restrict__ out)
{
  const int mbase = blockIdx.x * 64;
  const unsigned short* Wb = g_wbf + 49152;
  __shared__ unsigned short a_s[64 * 136];
  __shared__ unsigned short w_s[128 * 136];
  const int tid = threadIdx.x;
  {
    int r0 = tid >> 4, c = (tid & 15) * 8;
    for (int p = 0; p < 4; ++p)
      *(bf16x8*)&a_s[(p * 16 + r0) * 136 + c] =
          *(const bf16x8*)(A + (size_t)(mbase + p * 16 + r0) * 128 + c);
    for (int p = 0; p < 8; ++p)
      *(bf16x8*)&w_s[(p * 16 + r0) * 136 + c] =
          *(const bf16x8*)(Wb + (size_t)(p * 16 + r0) * 128 + c);
  }
  __syncthreads();
  const int wave = tid >> 6, lane = tid & 63, quad = lane >> 4, lr = lane & 15;
  f32x4 zero = {0.f, 0.f, 0.f, 0.f};
  f32x4 acc[8];
  for (int nb = 0; nb < 8; ++nb) acc[nb] = zero;
  for (int ks = 0; ks < 4; ++ks) {
    bf16x8 af = *(const bf16x8*)&a_s[(wave * 16 + lr) * 136 + ks * 32 + quad * 8];
    for (int nb = 0; nb < 8; ++nb) {
      bf16x8 bf = *(const bf16x8*)&w_s[(nb * 16 + lr) * 136 + ks * 32 + quad * 8];
      acc[nb] = MFMA16(af, bf, acc[nb]);
    }
  }
  for (int nb = 0; nb < 8; ++nb)
    for (int r = 0; r < 4; ++r) {
      int row = mbase + wave * 16 + quad * 4 + r;
      int col = nb * 16 + lr;
      out[(size_t)row * 128 + col] = acc[nb][r] + bias[col];
    }
}

extern "C" void kernel_launch(void* const* d_in, const int* in_sizes, int n_in,
                              void* d_out, int out_size, void* d_ws, size_t ws_size,
                              hipStream_t stream) {
  const float* q    = (const float*)d_in[0];
  const float* kv   = (const float*)d_in[1];
  const float* Wq   = (const float*)d_in[2];
  const float* Wkv  = (const float*)d_in[3];
  const float* Wout = (const float*)d_in[4];
  const float* bout = (const float*)d_in[5];
  float* out = (float*)d_out;

  const size_t NELEM = (size_t)131072 * 128;
  unsigned short* qp_b = (unsigned short*)d_ws;
  unsigned short* k_b  = qp_b + NELEM;
  unsigned short* vT_b = k_b + NELEM;   // [bh][128][2048]
  unsigned short* ao_b = vT_b + NELEM;

  // 128^-0.5 * log2(e): softmax computed in exp2 domain
  const float SCALE2 = 0.08838834764831845f * 1.4426950408889634f;

  conv_w<<<dim3(64), 256, 0, stream>>>(Wq, Wkv, Wout);
  proj_q<<<dim3(2048), 256, 0, stream>>>(q, qp_b, SCALE2);
  proj_kv<<<dim3(2048), 256, 0, stream>>>(kv, k_b, vT_b);
  attn_fused<<<dim3(256), 512, 0, stream>>>(qp_b, k_b, vT_b, ao_b);
  proj_out_k<<<dim3(2048), 256, 0, stream>>>(ao_b, bout, out);
}